// Round 1
// baseline (335.629 us; speedup 1.0000x reference)
//
#include <hip/hip_runtime.h>
#include <hip/hip_bf16.h>

// Problem constants
constexpr int S      = 4096;
constexpr int DMODEL = 1024;
constexpr int H      = 16;
constexpr int DK     = 64;

typedef __attribute__((ext_vector_type(8))) short          short8;
typedef __attribute__((ext_vector_type(4))) short          short4v;
typedef __attribute__((ext_vector_type(4))) float          float4v;
typedef __attribute__((ext_vector_type(4))) unsigned short ushort4v;
typedef __attribute__((ext_vector_type(8))) unsigned short ushort8;

// RNE float -> bf16 (bit pattern), and back
__device__ __forceinline__ unsigned short f2bf(float x) {
    unsigned u = __builtin_bit_cast(unsigned, x);
    u += 0x7FFFu + ((u >> 16) & 1u);
    return (unsigned short)(u >> 16);
}
__device__ __forceinline__ float bf2f(unsigned short h) {
    unsigned u = ((unsigned)h) << 16;
    return __builtin_bit_cast(float, u);
}
__device__ __forceinline__ float fexp2(float x) { return __builtin_amdgcn_exp2f(x); }

// async global->LDS DMA, 16B per lane; lds dest = wave-uniform base + lane*16
__device__ __forceinline__ void gl_lds16(const unsigned short* g, unsigned short* l) {
    __builtin_amdgcn_global_load_lds(
        (const __attribute__((address_space(1))) unsigned int*)g,
        (__attribute__((address_space(3))) unsigned int*)l, 16, 0, 0);
}

// ---------------------------------------------------------------------------
// Prep (fused, round-12): elementwise split of X inputs (z=0..2, round-3
// exact body) + all four weight transposes (z=3, round-10/11 body).  Fusing
// saves one launch gap; bodies are verbatim, only block-index remap.
// ---------------------------------------------------------------------------
__global__ __launch_bounds__(256) void prep_all(
    const float* __restrict__ Q, const float* __restrict__ K,
    const float* __restrict__ V,
    const float* __restrict__ WQ, const float* __restrict__ WK,
    const float* __restrict__ WV, const float* __restrict__ WO,
    unsigned short* __restrict__ QH, unsigned short* __restrict__ QL,
    unsigned short* __restrict__ KH, unsigned short* __restrict__ KL,
    unsigned short* __restrict__ Vb,
    unsigned short* __restrict__ WqtH, unsigned short* __restrict__ WqtL,
    unsigned short* __restrict__ WktH, unsigned short* __restrict__ WktL,
    unsigned short* __restrict__ Wvt,  unsigned short* __restrict__ WOt)
{
    const int zb = blockIdx.z;
    const int t  = threadIdx.x;

    if (zb < 3) {
        // ---- input split path (2048 blocks per z) ----
        const size_t base = ((size_t)blockIdx.x * 256 + t) * 8;
        const float* src = (zb == 0) ? Q : (zb == 1) ? K : V;
        const float4 a = *(const float4*)(src + base);
        const float4 b = *(const float4*)(src + base + 4);
        const float xs[8] = {a.x, a.y, a.z, a.w, b.x, b.y, b.z, b.w};
        ushort8 hv, lv;
#pragma unroll
        for (int j = 0; j < 8; ++j) {
            const unsigned short h = f2bf(xs[j]);
            hv[j] = h;
            lv[j] = f2bf(xs[j] - bf2f(h));
        }
        if (zb == 0)      { *(ushort8*)(QH + base) = hv; *(ushort8*)(QL + base) = lv; }
        else if (zb == 1) { *(ushort8*)(KH + base) = hv; *(ushort8*)(KL + base) = lv; }
        else              { *(ushort8*)(Vb + base) = hv; }
        return;
    }

    // ---- weight transpose path (first 1024 blocks of z=3) ----
    const int bb = blockIdx.x;
    if (bb >= 1024) return;
    const int zfull = bb >> 4;          // old blockIdx.z (0..63)
    const int which = zfull >> 4;
    const int z     = zfull & 15;
    const int r0    = (bb & 15) * 64;   // old blockIdx.x * 64

    __shared__ float Ts[64][65];

    const float* in;
    unsigned short *oh, *ol;
    int z_mult, rstride;
    if (which == 0)      { in = WQ; oh = WqtH; ol = WqtL; z_mult = 65536; rstride = 64; }
    else if (which == 1) { in = WK; oh = WktH; ol = WktL; z_mult = 65536; rstride = 64; }
    else if (which == 2) { in = WV; oh = Wvt;  ol = nullptr; z_mult = 65536; rstride = 64; }
    else                 { in = WO; oh = WOt;  ol = nullptr; z_mult = 64;    rstride = 1024; }

    const float* src = in + (size_t)z * z_mult;
#pragma unroll
    for (int i = 0; i < 4; ++i) {
        const int row = (t >> 4) + i * 16;
        const int col = (t & 15) * 4;
        const float4 v = *(const float4*)&src[(size_t)(r0 + row) * rstride + col];
        Ts[row][col + 0] = v.x; Ts[row][col + 1] = v.y;
        Ts[row][col + 2] = v.z; Ts[row][col + 3] = v.w;
    }
    __syncthreads();
#pragma unroll
    for (int i = 0; i < 4; ++i) {
        const int c  = (t >> 4) + i * 16;
        const int rb = (t & 15) * 4;
        ushort4v hv, lv;
#pragma unroll
        for (int j = 0; j < 4; ++j) {
            const float x = Ts[rb + j][c];
            const unsigned short h = f2bf(x);
            hv[j] = h;
            lv[j] = f2bf(x - bf2f(h));
        }
        const size_t o = (size_t)(z * 64 + c) * 1024 + r0 + rb;
        *(ushort4v*)&oh[o] = hv;
        if (ol) *(ushort4v*)&ol[o] = lv;
    }
}

// ---------------------------------------------------------------------------
// bf16 MFMA GEMM core (global_load_lds width=16 staging).
// EPI=0: fp32 -> C.
// EPI=1: bf16 hi/lo split -> O1/O2 (bit-identical to fp32-store + conv).
// EPI=2: TRANSPOSED bf16 -> O1 with O1[n0+n][m0+m] = f2bf(acc[m][n]),
//        O1 pitch 4096.  Replaces the separate transpose_v pass bit-exactly
//        (fp32 store/reload was exact; same f2bf).  LDS-staged 128x128
//        transpose, pitch 136 shorts (272B: 16B-aligned rows for b128
//        readout; ~2-way banks on read, ~4-way on the once-per-block write).
// ---------------------------------------------------------------------------
template <bool SPLIT, int EPI>
__device__ __forceinline__ void gemm_core(unsigned short* __restrict__ sm,
                                          const unsigned short* __restrict__ Ah,
                                          const unsigned short* __restrict__ Al,
                                          const unsigned short* __restrict__ Bh,
                                          const unsigned short* __restrict__ Bl,
                                          float* __restrict__ C,
                                          unsigned short* __restrict__ O1,
                                          unsigned short* __restrict__ O2,
                                          int m0, int n0)
{
    unsigned short* AsH = sm;            // [128][32]
    unsigned short* BsH = sm + 4096;
    unsigned short* AsL = sm + 8192;     // SPLIT only
    unsigned short* BsL = sm + 12288;

    const int t    = threadIdx.x;
    const int wave = t >> 6;
    const int lane = t & 63;
    const int quad = lane >> 4;
    const int l15  = lane & 15;
    const int wm   = (wave & 1) * 64;
    const int wn   = (wave >> 1) * 64;

    float4v acc[4][4];
#pragma unroll
    for (int mi = 0; mi < 4; ++mi)
#pragma unroll
        for (int ni = 0; ni < 4; ++ni)
#pragma unroll
            for (int r = 0; r < 4; ++r) acc[mi][ni][r] = 0.f;

    for (int k0 = 0; k0 < 1024; k0 += 32) {
        __syncthreads();   // prior iteration's LDS reads complete
#pragma unroll
        for (int i = 0; i < 2; ++i) {
            const int c   = t + 256 * i;
            const int row = c >> 2;
            const int kc  = (c & 3) * 8;
            const int lb  = (i * 256 + wave * 64) * 8;   // wave-uniform base (shorts)
            gl_lds16(&Ah[(size_t)(m0 + row) * 1024 + k0 + kc], AsH + lb);
            gl_lds16(&Bh[(size_t)(n0 + row) * 1024 + k0 + kc], BsH + lb);
            if (SPLIT) {
                gl_lds16(&Al[(size_t)(m0 + row) * 1024 + k0 + kc], AsL + lb);
                gl_lds16(&Bl[(size_t)(n0 + row) * 1024 + k0 + kc], BsL + lb);
            }
        }
        __syncthreads();   // vmcnt drained before barrier -> data visible

        short8 afh[4], bfh[4], afl[4], bfl[4];
#pragma unroll
        for (int mi = 0; mi < 4; ++mi)
            afh[mi] = *(const short8*)&AsH[(wm + mi * 16 + l15) * 32 + quad * 8];
#pragma unroll
        for (int ni = 0; ni < 4; ++ni)
            bfh[ni] = *(const short8*)&BsH[(wn + ni * 16 + l15) * 32 + quad * 8];
        if (SPLIT) {
#pragma unroll
            for (int mi = 0; mi < 4; ++mi)
                afl[mi] = *(const short8*)&AsL[(wm + mi * 16 + l15) * 32 + quad * 8];
#pragma unroll
            for (int ni = 0; ni < 4; ++ni)
                bfl[ni] = *(const short8*)&BsL[(wn + ni * 16 + l15) * 32 + quad * 8];
        }

#pragma unroll
        for (int mi = 0; mi < 4; ++mi)
#pragma unroll
            for (int ni = 0; ni < 4; ++ni) {
                acc[mi][ni] = __builtin_amdgcn_mfma_f32_16x16x32_bf16(
                    afh[mi], bfh[ni], acc[mi][ni], 0, 0, 0);
                if (SPLIT) {
                    acc[mi][ni] = __builtin_amdgcn_mfma_f32_16x16x32_bf16(
                        afh[mi], bfl[ni], acc[mi][ni], 0, 0, 0);
                    acc[mi][ni] = __builtin_amdgcn_mfma_f32_16x16x32_bf16(
                        afl[mi], bfh[ni], acc[mi][ni], 0, 0, 0);
                }
            }
    }

    if (EPI == 2) {
        // fused transpose epilogue: acc(m,n) -> O1[n][m] bf16
        __syncthreads();               // all waves done with As/Bs LDS reads
        unsigned short* Ts = sm;       // [128][136] pitch in shorts
#pragma unroll
        for (int mi = 0; mi < 4; ++mi)
#pragma unroll
            for (int ni = 0; ni < 4; ++ni) {
                ushort4v pk;
#pragma unroll
                for (int r = 0; r < 4; ++r) pk[r] = f2bf(acc[mi][ni][r]);
                *(ushort4v*)&Ts[(wn + ni * 16 + l15) * 136 + wm + mi * 16 + quad * 4] = pk;
            }
        __syncthreads();
#pragma unroll
        for (int p = 0; p < 8; ++p) {
            const int n = p * 16 + (t >> 4);
            const int m = (t & 15) * 8;
            *(ushort8*)&O1[(size_t)(n0 + n) * 4096 + m0 + m] =
                *(const ushort8*)&Ts[n * 136 + m];
        }
        return;
    }

#pragma unroll
    for (int mi = 0; mi < 4; ++mi)
#pragma unroll
        for (int r = 0; r < 4; ++r) {
            const int m = m0 + wm + mi * 16 + quad * 4 + r;
            if (EPI == 0) {
                float* cp = C + (size_t)m * 1024 + n0 + wn + l15;
#pragma unroll
                for (int ni = 0; ni < 4; ++ni) cp[ni * 16] = acc[mi][ni][r];
            } else {
                unsigned short* o1 = O1 + (size_t)m * 1024 + n0 + wn + l15;
                unsigned short* o2 = O2 + (size_t)m * 1024 + n0 + wn + l15;
#pragma unroll
                for (int ni = 0; ni < 4; ++ni) {
                    const float v = acc[mi][ni][r];
                    const unsigned short hh = f2bf(v);
                    o1[ni * 16] = hh;
                    o2[ni * 16] = f2bf(v - bf2f(hh));
                }
            }
        }
}

// Fused projections: z=0 Q(split->fp32 Qc), z=1 K(split->bf16 hi/lo direct),
// z=2 V(plain->bf16 TRANSPOSED Vt direct; transpose_v pass eliminated)
__global__ __launch_bounds__(256) void proj_mfma(
    const unsigned short* __restrict__ XqH, const unsigned short* __restrict__ XqL,
    const unsigned short* __restrict__ XkH, const unsigned short* __restrict__ XkL,
    const unsigned short* __restrict__ Xv,
    const unsigned short* __restrict__ WqtH, const unsigned short* __restrict__ WqtL,
    const unsigned short* __restrict__ WktH, const unsigned short* __restrict__ WktL,
    const unsigned short* __restrict__ Wvt,
    float* __restrict__ Qc,
    unsigned short* __restrict__ KHg, unsigned short* __restrict__ KLg,
    unsigned short* __restrict__ Vt)
{
    // max(SPLIT staging 4*4096, EPI2 transpose 128*136) shorts
    __shared__ __align__(16) unsigned short smem[17408];
    const int m0 = blockIdx.x * 128, n0 = blockIdx.y * 128;
    if (blockIdx.z == 0)
        gemm_core<true, 0>(smem, XqH, XqL, WqtH, WqtL, Qc, nullptr, nullptr, m0, n0);
    else if (blockIdx.z == 1)
        gemm_core<true, 1>(smem, XkH, XkL, WktH, WktL, nullptr, KHg, KLg, m0, n0);
    else
        gemm_core<false, 2>(smem, Xv, nullptr, Wvt, nullptr, nullptr, Vt, nullptr, m0, n0);
}

__global__ __launch_bounds__(256) void out_gemm_mfma(
    const unsigned short* __restrict__ Ocb,
    const unsigned short* __restrict__ WOt,
    float* __restrict__ out)
{
    __shared__ __align__(16) unsigned short smem[2 * 4096];
    gemm_core<false, 0>(smem, Ocb, nullptr, WOt, nullptr, out, nullptr, nullptr,
                        blockIdx.x * 128, blockIdx.y * 128);
}

// ---------------------------------------------------------------------------
// MFMA flash attention — round-8 structure (best measured: 140.5 µs, VGPR 76,
// occupancy 29.8%) + ONE change this round: s_setprio(1) wrapped around the
// S-phase and PV-phase MFMA clusters (m191-validated attn technique, +4-7%;
// blocks on a CU are at independent phases, so priority arbitration has
// something to do).  No register-pressure changes (r10/r11 lesson: pre-scale
// raised VGPR 76->92/100, occupancy ~20%, 160 µs — keep SCL per-tile).
// ---------------------------------------------------------------------------
__global__ __launch_bounds__(256) void attn_mfma(const float* __restrict__ Qc,
                                                 const unsigned short* __restrict__ KHg,
                                                 const unsigned short* __restrict__ KLg,
                                                 const unsigned short* __restrict__ Vtg,
                                                 unsigned short* __restrict__ Ocb)
{
    __shared__ __align__(16) short Khi[64][72];
    __shared__ __align__(16) short Klo[64][72];
    __shared__ __align__(16) short Vts[64][72];   // [dk][key]
    __shared__ __align__(16) short Pb[4][16][72];

    const int bid = blockIdx.x;
    const int h   = bid & 15;
    const int qt  = 63 - (bid >> 4);   // longest tiles dispatch first
    const int q0  = qt * 64;

    const int t    = threadIdx.x;
    const int wave = t >> 6;
    const int lane = t & 63;
    const int quad = lane >> 4;
    const int l15  = lane & 15;

    constexpr float SCL = 0.18033688011112042f;   // 0.125 * log2(e)

    // Q A-fragments, split hi/lo from fp32 (once per block)
    short8 qhi[2], qlo[2];
    {
        const int qrow = q0 + wave * 16 + l15;
        const float* qp = Qc + (size_t)qrow * DMODEL + h * 64 + quad * 8;
#pragma unroll
        for (int ks = 0; ks < 2; ++ks) {
            float4 a = *(const float4*)(qp + ks * 32);
            float4 b = *(const float4*)(qp + ks * 32 + 4);
            const float xs[8] = {a.x, a.y, a.z, a.w, b.x, b.y, b.z, b.w};
#pragma unroll
            for (int j = 0; j < 8; ++j) {
                const unsigned short hi = f2bf(xs[j]);
                const unsigned short lo = f2bf(xs[j] - bf2f(hi));
                qhi[ks][j] = (short)hi;
                qlo[ks][j] = (short)lo;
            }
        }
    }

    // all-ones B fragment: B[k][0] = 1.0, other cols 0  (row-sum MFMA)
    short8 bones;
    {
        const short ob = (l15 == 0) ? (short)0x3F80 : (short)0;
#pragma unroll
        for (int j = 0; j < 8; ++j) bones[j] = ob;
    }

    float m_r[4] = {-1e30f, -1e30f, -1e30f, -1e30f};
    float4v lacc;
    float4v oacc[4];
#pragma unroll
    for (int r = 0; r < 4; ++r) lacc[r] = 0.f;
#pragma unroll
    for (int nt = 0; nt < 4; ++nt)
#pragma unroll
        for (int r = 0; r < 4; ++r) oacc[nt][r] = 0.f;

    // staging assignment: thread covers rows {srow, srow+32}, 16B col chunk
    const int srow = t >> 3;
    const int soff = (t & 7) * 8;

    // prefetch registers, initial load for jt = 0
    ushort8 kh[2], kl[2], vt[2];
#pragma unroll
    for (int i = 0; i < 2; ++i) {
        const int row = srow + 32 * i;
        kh[i] = *(const ushort8*)&KHg[(size_t)row * 1024 + h * 64 + soff];
        kl[i] = *(const ushort8*)&KLg[(size_t)row * 1024 + h * 64 + soff];
        vt[i] = *(const ushort8*)&Vtg[(size_t)(h * 64 + row) * 4096 + soff];
    }

    for (int jt = 0; jt <= qt; ++jt) {
        const int j0 = jt * 64;
        // --- stage prefetched vectors (conflict-free ds_write_b128) ---
#pragma unroll
        for (int i = 0; i < 2; ++i) {
            const int row = srow + 32 * i;
            *(ushort8*)&Khi[row][soff] = kh[i];
            *(ushort8*)&Klo[row][soff] = kl[i];
            *(ushort8*)&Vts[row][soff] = vt[i];
        }
        __syncthreads();

        // --- prefetch next tile (overlaps compute below) ---
        if (jt < qt) {
            const int jn = j0 + 64;
#pragma unroll
            for (int i = 0; i < 2; ++i) {
                const int row = srow + 32 * i;
                kh[i] = *(const ushort8*)&KHg[(size_t)(jn + row) * 1024 + h * 64 + soff];
                kl[i] = *(const ushort8*)&KLg[(size_t)(jn + row) * 1024 + h * 64 + soff];
                vt[i] = *(const ushort8*)&Vtg[(size_t)(h * 64 + row) * 4096 + jn + soff];
            }
        }

        // --- S = Q K^T (split bf16, fp32 accum) ---
        float4v sacc[4];
#pragma unroll
        for (int nt = 0; nt < 4; ++nt)
#pragma unroll
            for (int r = 0; r < 4; ++r) sacc[nt][r] = 0.f;
        __builtin_amdgcn_s_setprio(1);
#pragma unroll
        for (int nt = 0; nt < 4; ++nt) {
            const int key = nt * 16 + l15;
#pragma unroll
            for (int ks = 0; ks < 2; ++ks) {
                const short8 bh = *(const short8*)&Khi[key][ks * 32 + quad * 8];
                const short8 bl = *(const short8*)&Klo[key][ks * 32 + quad * 8];
                sacc[nt] = __builtin_amdgcn_mfma_f32_16x16x32_bf16(qhi[ks], bh, sacc[nt], 0, 0, 0);
                sacc[nt] = __builtin_amdgcn_mfma_f32_16x16x32_bf16(qhi[ks], bl, sacc[nt], 0, 0, 0);
                sacc[nt] = __builtin_amdgcn_mfma_f32_16x16x32_bf16(qlo[ks], bh, sacc[nt], 0, 0, 0);
            }
        }
        __builtin_amdgcn_s_setprio(0);

        // --- scale to base-2; causal mask only on diagonal tile ---
        if (jt == qt) {
#pragma unroll
            for (int nt = 0; nt < 4; ++nt) {
                const int jg = j0 + nt * 16 + l15;
#pragma unroll
                for (int r = 0; r < 4; ++r) {
                    const int qg = q0 + wave * 16 + quad * 4 + r;
                    const float v = sacc[nt][r] * SCL;
                    sacc[nt][r] = (jg > qg) ? -1e9f : v;
                }
            }
        } else {
#pragma unroll
            for (int nt = 0; nt < 4; ++nt)
#pragma unroll
                for (int r = 0; r < 4; ++r)
                    sacc[nt][r] *= SCL;
        }

        // --- online softmax max-path ---
        float rmax[4];
#pragma unroll
        for (int r = 0; r < 4; ++r)
            rmax[r] = fmaxf(fmaxf(sacc[0][r], sacc[1][r]), fmaxf(sacc[2][r], sacc[3][r]));
#pragma unroll
        for (int off = 1; off < 16; off <<= 1)
#pragma unroll
            for (int r = 0; r < 4; ++r)
                rmax[r] = fmaxf(rmax[r], __shfl_xor(rmax[r], off));

        float alpha[4];
#pragma unroll
        for (int r = 0; r < 4; ++r) {
            const float mn = fmaxf(m_r[r], rmax[r]);
            alpha[r] = fexp2(m_r[r] - mn);
            m_r[r] = mn;
        }

        // --- exp2 (sum folded into PV MFMA) ---
#pragma unroll
        for (int nt = 0; nt < 4; ++nt)
#pragma unroll
            for (int r = 0; r < 4; ++r)
                sacc[nt][r] = fexp2(sacc[nt][r] - m_r[r]);

#pragma unroll
        for (int r = 0; r < 4; ++r) lacc[r] *= alpha[r];
#pragma unroll
        for (int nt = 0; nt < 4; ++nt)
#pragma unroll
            for (int r = 0; r < 4; ++r)
                oacc[nt][r] *= alpha[r];

        // --- P (C-layout) -> per-wave LDS strip -> A-layout (f2bf, RNE) ---
#pragma unroll
        for (int nt = 0; nt < 4; ++nt)
#pragma unroll
            for (int r = 0; r < 4; ++r)
                Pb[wave][quad * 4 + r][nt * 16 + l15] = (short)f2bf(sacc[nt][r]);
        __asm__ volatile("s_waitcnt lgkmcnt(0)" ::: "memory");

        // --- O += P @ V, and l += P @ 1 ---
        short8 af[2];
        af[0] = *(const short8*)&Pb[wave][l15][quad * 8];
        af[1] = *(const short8*)&Pb[wave][l15][32 + quad * 8];
        __builtin_amdgcn_s_setprio(1);
#pragma unroll
        for (int nt = 0; nt < 4; ++nt) {
            const int dk = nt * 16 + l15;
#pragma unroll
            for (int ks = 0; ks < 2; ++ks) {
                const short8 bv = *(const short8*)&Vts[dk][ks * 32 + quad * 8];
                oacc[nt] = __builtin_amdgcn_mfma_f32_16x16x32_bf16(af[ks], bv, oacc[nt], 0, 0, 0);
            }
        }
        lacc = __builtin_amdgcn_mfma_f32_16x16x32_bf16(af[0], bones, lacc, 0, 0, 0);
        lacc = __builtin_amdgcn_mfma_f32_16x16x32_bf16(af[1], bones, lacc, 0, 0, 0);
        __builtin_amdgcn_s_setprio(0);
        __syncthreads();   // LDS tiles free before restaging
    }

    // --- epilogue: broadcast l from col-0 lanes, normalize, write bf16 ---
#pragma unroll
    for (int r = 0; r < 4; ++r) {
        const float lsum = __shfl(lacc[r], (lane & 48));   // lane quad*16 (l15==0)
        const float inv  = 1.0f / lsum;
        const int qg = q0 + wave * 16 + quad * 4 + r;
        unsigned short* op = Ocb + (size_t)qg * DMODEL + h * 64 + l15;
#pragma unroll
        for (int nt = 0; nt < 4; ++nt)
            op[nt * 16] = f2bf(oacc[nt][r] * inv);
    }
}

extern "C" void kernel_launch(void* const* d_in, const int* in_sizes, int n_in,
                              void* d_out, int out_size, void* d_ws, size_t ws_size,
                              hipStream_t stream)
{
    const float* Q  = (const float*)d_in[0];
    const float* K  = (const float*)d_in[1];
    const float* V  = (const float*)d_in[2];
    const float* WQ = (const float*)d_in[3];
    const float* WK = (const float*)d_in[4];
    const float* WV = (const float*)d_in[5];
    const float* WO = (const float*)d_in[6];

    float* out = (float*)d_out;

    // Workspace carve-up (~100 MB).  Vt gets its OWN slot (old fp32-Vc slot):
    // it is written during proj_mfma while Xv is still being read by the same
    // GEMM, so it must NOT alias Xv.
    const size_t SD4 = (size_t)S * DMODEL * 4;       // fp32 S x D  (16 MB)
    const size_t SD2 = (size_t)S * DMODEL * 2;       // bf16 S x D  ( 8 MB)
    const size_t W2  = (size_t)DMODEL * DMODEL * 2;  // bf16 D x D  ( 2 MB)
    char* p = (char*)d_ws;
    auto take = [&](size_t b) { char* r = p; p += b; return r; };

    float* Qc = (float*)take(SD4);
    unsigned short* KHg = (unsigned short*)take(SD2);
    unsigned short* KLg = (unsigned short*)take(SD2);
    unsigned short* Vtg = (unsigned short*)take(SD2);   // bf16 [1024][4096]
    unsigned short* XqH = (unsigned short*)take(SD2);
    unsigned short* XqL = (unsigned short*)take(SD2);
    unsigned short* XkH = (unsigned short*)take(SD2);
    unsigned short* XkL = (unsigned short*)take(SD2);
    unsigned short* Xv  = (unsigned short*)take(SD2);
    unsigned short* WqtH = (unsigned short*)take(W2);
    unsigned short* WqtL = (unsigned short*)take(W2);
    unsigned short* WktH = (unsigned short*)take(W2);
    unsigned short* WktL = (unsigned short*)take(W2);
    unsigned short* Wvt  = (unsigned short*)take(W2);
    unsigned short* WOt  = (unsigned short*)take(W2);
    unsigned short* Ocb  = (unsigned short*)take(SD2);

    // 1) input splits + all weight transposes in ONE launch
    prep_all<<<dim3(2048, 1, 4), 256, 0, stream>>>(
        Q, K, V, WQ, WK, WV, WO,
        XqH, XqL, XkH, XkL, Xv, WqtH, WqtL, WktH, WktL, Wvt, WOt);
    // 2) projections: Q -> fp32 Qc; K -> bf16 hi/lo direct;
    //    V -> bf16 TRANSPOSED Vt direct (transpose_v pass eliminated)
    proj_mfma<<<dim3(S / 128, DMODEL / 128, 3), 256, 0, stream>>>(
        XqH, XqL, XkH, XkL, Xv, WqtH, WqtL, WktH, WktL, Wvt, Qc, KHg, KLg, Vtg);
    // 3) causal flash attention -> bf16 Ocb  (round-8 structure + setprio)
    attn_mfma<<<dim3((S / 64) * H), 256, 0, stream>>>(Qc, KHg, KLg, Vtg, Ocb);
    // 4) output projection
    out_gemm_mfma<<<dim3(S / 128, DMODEL / 128), 256, 0, stream>>>(Ocb, WOt, out);
}

// Round 3
// 332.859 us; speedup vs baseline: 1.0083x; 1.0083x over previous
//
#include <hip/hip_runtime.h>
#include <hip/hip_bf16.h>

// Problem constants
constexpr int S      = 4096;
constexpr int DMODEL = 1024;
constexpr int H      = 16;
constexpr int DK     = 64;

typedef __attribute__((ext_vector_type(8))) short          short8;
typedef __attribute__((ext_vector_type(4))) short          short4v;
typedef __attribute__((ext_vector_type(4))) float          float4v;
typedef __attribute__((ext_vector_type(4))) unsigned short ushort4v;
typedef __attribute__((ext_vector_type(8))) unsigned short ushort8;

// RNE float -> bf16 (bit pattern), and back
__device__ __forceinline__ unsigned short f2bf(float x) {
    unsigned u = __builtin_bit_cast(unsigned, x);
    u += 0x7FFFu + ((u >> 16) & 1u);
    return (unsigned short)(u >> 16);
}
__device__ __forceinline__ float bf2f(unsigned short h) {
    unsigned u = ((unsigned)h) << 16;
    return __builtin_bit_cast(float, u);
}
__device__ __forceinline__ float fexp2(float x) { return __builtin_amdgcn_exp2f(x); }

// async global->LDS DMA, 16B per lane; lds dest = wave-uniform base + lane*16
__device__ __forceinline__ void gl_lds16(const unsigned short* g, unsigned short* l) {
    __builtin_amdgcn_global_load_lds(
        (const __attribute__((address_space(1))) unsigned int*)g,
        (__attribute__((address_space(3))) unsigned int*)l, 16, 0, 0);
}

// ---------------------------------------------------------------------------
// Prep (fused): elementwise split of X inputs (z=0..2) + all four weight
// transposes (z=3).  Verbatim from round 1 (passed).
// ---------------------------------------------------------------------------
__global__ __launch_bounds__(256) void prep_all(
    const float* __restrict__ Q, const float* __restrict__ K,
    const float* __restrict__ V,
    const float* __restrict__ WQ, const float* __restrict__ WK,
    const float* __restrict__ WV, const float* __restrict__ WO,
    unsigned short* __restrict__ QH, unsigned short* __restrict__ QL,
    unsigned short* __restrict__ KH, unsigned short* __restrict__ KL,
    unsigned short* __restrict__ Vb,
    unsigned short* __restrict__ WqtH, unsigned short* __restrict__ WqtL,
    unsigned short* __restrict__ WktH, unsigned short* __restrict__ WktL,
    unsigned short* __restrict__ Wvt,  unsigned short* __restrict__ WOt)
{
    const int zb = blockIdx.z;
    const int t  = threadIdx.x;

    if (zb < 3) {
        // ---- input split path (2048 blocks per z) ----
        const size_t base = ((size_t)blockIdx.x * 256 + t) * 8;
        const float* src = (zb == 0) ? Q : (zb == 1) ? K : V;
        const float4 a = *(const float4*)(src + base);
        const float4 b = *(const float4*)(src + base + 4);
        const float xs[8] = {a.x, a.y, a.z, a.w, b.x, b.y, b.z, b.w};
        ushort8 hv, lv;
#pragma unroll
        for (int j = 0; j < 8; ++j) {
            const unsigned short h = f2bf(xs[j]);
            hv[j] = h;
            lv[j] = f2bf(xs[j] - bf2f(h));
        }
        if (zb == 0)      { *(ushort8*)(QH + base) = hv; *(ushort8*)(QL + base) = lv; }
        else if (zb == 1) { *(ushort8*)(KH + base) = hv; *(ushort8*)(KL + base) = lv; }
        else              { *(ushort8*)(Vb + base) = hv; }
        return;
    }

    // ---- weight transpose path (first 1024 blocks of z=3) ----
    const int bb = blockIdx.x;
    if (bb >= 1024) return;
    const int zfull = bb >> 4;          // old blockIdx.z (0..63)
    const int which = zfull >> 4;
    const int z     = zfull & 15;
    const int r0    = (bb & 15) * 64;   // old blockIdx.x * 64

    __shared__ float Ts[64][65];

    const float* in;
    unsigned short *oh, *ol;
    int z_mult, rstride;
    if (which == 0)      { in = WQ; oh = WqtH; ol = WqtL; z_mult = 65536; rstride = 64; }
    else if (which == 1) { in = WK; oh = WktH; ol = WktL; z_mult = 65536; rstride = 64; }
    else if (which == 2) { in = WV; oh = Wvt;  ol = nullptr; z_mult = 65536; rstride = 64; }
    else                 { in = WO; oh = WOt;  ol = nullptr; z_mult = 64;    rstride = 1024; }

    const float* src = in + (size_t)z * z_mult;
#pragma unroll
    for (int i = 0; i < 4; ++i) {
        const int row = (t >> 4) + i * 16;
        const int col = (t & 15) * 4;
        const float4 v = *(const float4*)&src[(size_t)(r0 + row) * rstride + col];
        Ts[row][col + 0] = v.x; Ts[row][col + 1] = v.y;
        Ts[row][col + 2] = v.z; Ts[row][col + 3] = v.w;
    }
    __syncthreads();
#pragma unroll
    for (int i = 0; i < 4; ++i) {
        const int c  = (t >> 4) + i * 16;
        const int rb = (t & 15) * 4;
        ushort4v hv, lv;
#pragma unroll
        for (int j = 0; j < 4; ++j) {
            const float x = Ts[rb + j][c];
            const unsigned short h = f2bf(x);
            hv[j] = h;
            lv[j] = f2bf(x - bf2f(h));
        }
        const size_t o = (size_t)(z * 64 + c) * 1024 + r0 + rb;
        *(ushort4v*)&oh[o] = hv;
        if (ol) *(ushort4v*)&ol[o] = lv;
    }
}

// ---------------------------------------------------------------------------
// bf16 MFMA GEMM core (global_load_lds width=16 staging).
// EPI=0: fp32 -> C.
// EPI=1: bf16 hi/lo split -> O1/O2.
// EPI=2: TRANSPOSED bf16 -> O1 (pitch 4096), replaces transpose_v bit-exactly.
// ---------------------------------------------------------------------------
template <bool SPLIT, int EPI>
__device__ __forceinline__ void gemm_core(unsigned short* __restrict__ sm,
                                          const unsigned short* __restrict__ Ah,
                                          const unsigned short* __restrict__ Al,
                                          const unsigned short* __restrict__ Bh,
                                          const unsigned short* __restrict__ Bl,
                                          float* __restrict__ C,
                                          unsigned short* __restrict__ O1,
                                          unsigned short* __restrict__ O2,
                                          int m0, int n0)
{
    unsigned short* AsH = sm;            // [128][32]
    unsigned short* BsH = sm + 4096;
    unsigned short* AsL = sm + 8192;     // SPLIT only
    unsigned short* BsL = sm + 12288;

    const int t    = threadIdx.x;
    const int wave = t >> 6;
    const int lane = t & 63;
    const int quad = lane >> 4;
    const int l15  = lane & 15;
    const int wm   = (wave & 1) * 64;
    const int wn   = (wave >> 1) * 64;

    float4v acc[4][4];
#pragma unroll
    for (int mi = 0; mi < 4; ++mi)
#pragma unroll
        for (int ni = 0; ni < 4; ++ni)
#pragma unroll
            for (int r = 0; r < 4; ++r) acc[mi][ni][r] = 0.f;

    for (int k0 = 0; k0 < 1024; k0 += 32) {
        __syncthreads();   // prior iteration's LDS reads complete
#pragma unroll
        for (int i = 0; i < 2; ++i) {
            const int c   = t + 256 * i;
            const int row = c >> 2;
            const int kc  = (c & 3) * 8;
            const int lb  = (i * 256 + wave * 64) * 8;   // wave-uniform base (shorts)
            gl_lds16(&Ah[(size_t)(m0 + row) * 1024 + k0 + kc], AsH + lb);
            gl_lds16(&Bh[(size_t)(n0 + row) * 1024 + k0 + kc], BsH + lb);
            if (SPLIT) {
                gl_lds16(&Al[(size_t)(m0 + row) * 1024 + k0 + kc], AsL + lb);
                gl_lds16(&Bl[(size_t)(n0 + row) * 1024 + k0 + kc], BsL + lb);
            }
        }
        __syncthreads();   // vmcnt drained before barrier -> data visible

        short8 afh[4], bfh[4], afl[4], bfl[4];
#pragma unroll
        for (int mi = 0; mi < 4; ++mi)
            afh[mi] = *(const short8*)&AsH[(wm + mi * 16 + l15) * 32 + quad * 8];
#pragma unroll
        for (int ni = 0; ni < 4; ++ni)
            bfh[ni] = *(const short8*)&BsH[(wn + ni * 16 + l15) * 32 + quad * 8];
        if (SPLIT) {
#pragma unroll
            for (int mi = 0; mi < 4; ++mi)
                afl[mi] = *(const short8*)&AsL[(wm + mi * 16 + l15) * 32 + quad * 8];
#pragma unroll
            for (int ni = 0; ni < 4; ++ni)
                bfl[ni] = *(const short8*)&BsL[(wn + ni * 16 + l15) * 32 + quad * 8];
        }

#pragma unroll
        for (int mi = 0; mi < 4; ++mi)
#pragma unroll
            for (int ni = 0; ni < 4; ++ni) {
                acc[mi][ni] = __builtin_amdgcn_mfma_f32_16x16x32_bf16(
                    afh[mi], bfh[ni], acc[mi][ni], 0, 0, 0);
                if (SPLIT) {
                    acc[mi][ni] = __builtin_amdgcn_mfma_f32_16x16x32_bf16(
                        afh[mi], bfl[ni], acc[mi][ni], 0, 0, 0);
                    acc[mi][ni] = __builtin_amdgcn_mfma_f32_16x16x32_bf16(
                        afl[mi], bfh[ni], acc[mi][ni], 0, 0, 0);
                }
            }
    }

    if (EPI == 2) {
        // fused transpose epilogue: acc(m,n) -> O1[n][m] bf16
        __syncthreads();               // all waves done with As/Bs LDS reads
        unsigned short* Ts = sm;       // [128][136] pitch in shorts
#pragma unroll
        for (int mi = 0; mi < 4; ++mi)
#pragma unroll
            for (int ni = 0; ni < 4; ++ni) {
                ushort4v pk;
#pragma unroll
                for (int r = 0; r < 4; ++r) pk[r] = f2bf(acc[mi][ni][r]);
                *(ushort4v*)&Ts[(wn + ni * 16 + l15) * 136 + wm + mi * 16 + quad * 4] = pk;
            }
        __syncthreads();
#pragma unroll
        for (int p = 0; p < 8; ++p) {
            const int n = p * 16 + (t >> 4);
            const int m = (t & 15) * 8;
            *(ushort8*)&O1[(size_t)(n0 + n) * 4096 + m0 + m] =
                *(const ushort8*)&Ts[n * 136 + m];
        }
        return;
    }

#pragma unroll
    for (int mi = 0; mi < 4; ++mi)
#pragma unroll
        for (int r = 0; r < 4; ++r) {
            const int m = m0 + wm + mi * 16 + quad * 4 + r;
            if (EPI == 0) {
                float* cp = C + (size_t)m * 1024 + n0 + wn + l15;
#pragma unroll
                for (int ni = 0; ni < 4; ++ni) cp[ni * 16] = acc[mi][ni][r];
            } else {
                unsigned short* o1 = O1 + (size_t)m * 1024 + n0 + wn + l15;
                unsigned short* o2 = O2 + (size_t)m * 1024 + n0 + wn + l15;
#pragma unroll
                for (int ni = 0; ni < 4; ++ni) {
                    const float v = acc[mi][ni][r];
                    const unsigned short hh = f2bf(v);
                    o1[ni * 16] = hh;
                    o2[ni * 16] = f2bf(v - bf2f(hh));
                }
            }
        }
}

// Fused projections: z=0 Q(split->fp32 Qc), z=1 K(split->bf16 hi/lo direct),
// z=2 V(plain->bf16 TRANSPOSED Vt direct)
__global__ __launch_bounds__(256) void proj_mfma(
    const unsigned short* __restrict__ XqH, const unsigned short* __restrict__ XqL,
    const unsigned short* __restrict__ XkH, const unsigned short* __restrict__ XkL,
    const unsigned short* __restrict__ Xv,
    const unsigned short* __restrict__ WqtH, const unsigned short* __restrict__ WqtL,
    const unsigned short* __restrict__ WktH, const unsigned short* __restrict__ WktL,
    const unsigned short* __restrict__ Wvt,
    float* __restrict__ Qc,
    unsigned short* __restrict__ KHg, unsigned short* __restrict__ KLg,
    unsigned short* __restrict__ Vt)
{
    // max(SPLIT staging 4*4096, EPI2 transpose 128*136) shorts
    __shared__ __align__(16) unsigned short smem[17408];
    const int m0 = blockIdx.x * 128, n0 = blockIdx.y * 128;
    if (blockIdx.z == 0)
        gemm_core<true, 0>(smem, XqH, XqL, WqtH, WqtL, Qc, nullptr, nullptr, m0, n0);
    else if (blockIdx.z == 1)
        gemm_core<true, 1>(smem, XkH, XkL, WktH, WktL, nullptr, KHg, KLg, m0, n0);
    else
        gemm_core<false, 2>(smem, Xv, nullptr, Wvt, nullptr, nullptr, Vt, nullptr, m0, n0);
}

__global__ __launch_bounds__(256) void out_gemm_mfma(
    const unsigned short* __restrict__ Ocb,
    const unsigned short* __restrict__ WOt,
    float* __restrict__ out)
{
    __shared__ __align__(16) unsigned short smem[2 * 4096];
    gemm_core<false, 0>(smem, Ocb, nullptr, WOt, nullptr, out, nullptr, nullptr,
                        blockIdx.x * 128, blockIdx.y * 128);
}

// ---------------------------------------------------------------------------
// MFMA flash attention — 8-wave blocks, QBLK=128, KVBLK=64 (round-2
// restructure, resubmitted verbatim after infra-only bench failure).
// Per-wave inner code is round-8 VERBATIM (no setprio: round-1 A/B showed
// 140.5 -> 146.8 µs with it — lockstep barrier structure, m190 regime).
//   * One K/V staging + barrier pair feeds 8 waves (was 4): staging traffic
//     and barrier count per unit work halve.
//   * Waves 0-3 see one extra fully-masked tile per block: S=-1e9 ->
//     exp2 underflows to exactly 0, alpha=exp2(0)=1 -> bit-identical output.
//   * Load-balance pairing: qb = g<16 ? 31-g : g-16 puts one long + one
//     complementary short block on each CU (2 blocks/CU, uniform 66 iters).
// ---------------------------------------------------------------------------
__global__ __launch_bounds__(512) void attn_mfma(const float* __restrict__ Qc,
                                                 const unsigned short* __restrict__ KHg,
                                                 const unsigned short* __restrict__ KLg,
                                                 const unsigned short* __restrict__ Vtg,
                                                 unsigned short* __restrict__ Ocb)
{
    __shared__ __align__(16) short Khi[64][72];
    __shared__ __align__(16) short Klo[64][72];
    __shared__ __align__(16) short Vts[64][72];   // [dk][key]
    __shared__ __align__(16) short Pb[8][16][72];

    const int bid = blockIdx.x;
    const int h   = bid & 15;
    const int g   = bid >> 4;                       // 0..31
    const int qb  = (g < 16) ? (31 - g) : (g - 16); // long/short pairing
    const int q0  = qb * 128;
    const int jtmax = 2 * qb + 1;

    const int t    = threadIdx.x;
    const int wave = t >> 6;      // 0..7
    const int lane = t & 63;
    const int quad = lane >> 4;
    const int l15  = lane & 15;

    constexpr float SCL = 0.18033688011112042f;   // 0.125 * log2(e)

    // Q A-fragments, split hi/lo from fp32 (once per block)
    short8 qhi[2], qlo[2];
    {
        const int qrow = q0 + wave * 16 + l15;
        const float* qp = Qc + (size_t)qrow * DMODEL + h * 64 + quad * 8;
#pragma unroll
        for (int ks = 0; ks < 2; ++ks) {
            float4 a = *(const float4*)(qp + ks * 32);
            float4 b = *(const float4*)(qp + ks * 32 + 4);
            const float xs[8] = {a.x, a.y, a.z, a.w, b.x, b.y, b.z, b.w};
#pragma unroll
            for (int j = 0; j < 8; ++j) {
                const unsigned short hi = f2bf(xs[j]);
                const unsigned short lo = f2bf(xs[j] - bf2f(hi));
                qhi[ks][j] = (short)hi;
                qlo[ks][j] = (short)lo;
            }
        }
    }

    // all-ones B fragment: B[k][0] = 1.0, other cols 0  (row-sum MFMA)
    short8 bones;
    {
        const short ob = (l15 == 0) ? (short)0x3F80 : (short)0;
#pragma unroll
        for (int j = 0; j < 8; ++j) bones[j] = ob;
    }

    float m_r[4] = {-1e30f, -1e30f, -1e30f, -1e30f};
    float4v lacc;
    float4v oacc[4];
#pragma unroll
    for (int r = 0; r < 4; ++r) lacc[r] = 0.f;
#pragma unroll
    for (int nt = 0; nt < 4; ++nt)
#pragma unroll
        for (int r = 0; r < 4; ++r) oacc[nt][r] = 0.f;

    // staging assignment: 512 threads cover 64 rows x 8 col-chunks, one
    // ushort8 per array per thread
    const int srow = t >> 3;        // 0..63
    const int soff = (t & 7) * 8;   // 0..56

    // prefetch registers, initial load for jt = 0
    ushort8 kh, kl, vt;
    kh = *(const ushort8*)&KHg[(size_t)srow * 1024 + h * 64 + soff];
    kl = *(const ushort8*)&KLg[(size_t)srow * 1024 + h * 64 + soff];
    vt = *(const ushort8*)&Vtg[(size_t)(h * 64 + srow) * 4096 + soff];

    for (int jt = 0; jt <= jtmax; ++jt) {
        const int j0 = jt * 64;
        // --- stage prefetched vectors (ds_write_b128) ---
        *(ushort8*)&Khi[srow][soff] = kh;
        *(ushort8*)&Klo[srow][soff] = kl;
        *(ushort8*)&Vts[srow][soff] = vt;
        __syncthreads();

        // --- prefetch next tile (overlaps compute below) ---
        if (jt < jtmax) {
            const int jn = j0 + 64;
            kh = *(const ushort8*)&KHg[(size_t)(jn + srow) * 1024 + h * 64 + soff];
            kl = *(const ushort8*)&KLg[(size_t)(jn + srow) * 1024 + h * 64 + soff];
            vt = *(const ushort8*)&Vtg[(size_t)(h * 64 + srow) * 4096 + jn + soff];
        }

        // --- S = Q K^T (split bf16, fp32 accum) ---
        float4v sacc[4];
#pragma unroll
        for (int nt = 0; nt < 4; ++nt)
#pragma unroll
            for (int r = 0; r < 4; ++r) sacc[nt][r] = 0.f;
#pragma unroll
        for (int nt = 0; nt < 4; ++nt) {
            const int key = nt * 16 + l15;
#pragma unroll
            for (int ks = 0; ks < 2; ++ks) {
                const short8 bh = *(const short8*)&Khi[key][ks * 32 + quad * 8];
                const short8 bl = *(const short8*)&Klo[key][ks * 32 + quad * 8];
                sacc[nt] = __builtin_amdgcn_mfma_f32_16x16x32_bf16(qhi[ks], bh, sacc[nt], 0, 0, 0);
                sacc[nt] = __builtin_amdgcn_mfma_f32_16x16x32_bf16(qhi[ks], bl, sacc[nt], 0, 0, 0);
                sacc[nt] = __builtin_amdgcn_mfma_f32_16x16x32_bf16(qlo[ks], bh, sacc[nt], 0, 0, 0);
            }
        }

        // --- scale to base-2; causal mask when tile reaches this wave's
        //     diagonal (includes the fully-masked extra tile for low waves) ---
        if (j0 + 63 > q0 + wave * 16) {
#pragma unroll
            for (int nt = 0; nt < 4; ++nt) {
                const int jg = j0 + nt * 16 + l15;
#pragma unroll
                for (int r = 0; r < 4; ++r) {
                    const int qg = q0 + wave * 16 + quad * 4 + r;
                    const float v = sacc[nt][r] * SCL;
                    sacc[nt][r] = (jg > qg) ? -1e9f : v;
                }
            }
        } else {
#pragma unroll
            for (int nt = 0; nt < 4; ++nt)
#pragma unroll
                for (int r = 0; r < 4; ++r)
                    sacc[nt][r] *= SCL;
        }

        // --- online softmax max-path ---
        float rmax[4];
#pragma unroll
        for (int r = 0; r < 4; ++r)
            rmax[r] = fmaxf(fmaxf(sacc[0][r], sacc[1][r]), fmaxf(sacc[2][r], sacc[3][r]));
#pragma unroll
        for (int off = 1; off < 16; off <<= 1)
#pragma unroll
            for (int r = 0; r < 4; ++r)
                rmax[r] = fmaxf(rmax[r], __shfl_xor(rmax[r], off));

        float alpha[4];
#pragma unroll
        for (int r = 0; r < 4; ++r) {
            const float mn = fmaxf(m_r[r], rmax[r]);
            alpha[r] = fexp2(m_r[r] - mn);
            m_r[r] = mn;
        }

        // --- exp2 (sum folded into PV MFMA) ---
#pragma unroll
        for (int nt = 0; nt < 4; ++nt)
#pragma unroll
            for (int r = 0; r < 4; ++r)
                sacc[nt][r] = fexp2(sacc[nt][r] - m_r[r]);

#pragma unroll
        for (int r = 0; r < 4; ++r) lacc[r] *= alpha[r];
#pragma unroll
        for (int nt = 0; nt < 4; ++nt)
#pragma unroll
            for (int r = 0; r < 4; ++r)
                oacc[nt][r] *= alpha[r];

        // --- P (C-layout) -> per-wave LDS strip -> A-layout (f2bf, RNE) ---
#pragma unroll
        for (int nt = 0; nt < 4; ++nt)
#pragma unroll
            for (int r = 0; r < 4; ++r)
                Pb[wave][quad * 4 + r][nt * 16 + l15] = (short)f2bf(sacc[nt][r]);
        __asm__ volatile("s_waitcnt lgkmcnt(0)" ::: "memory");

        // --- O += P @ V, and l += P @ 1 ---
        short8 af[2];
        af[0] = *(const short8*)&Pb[wave][l15][quad * 8];
        af[1] = *(const short8*)&Pb[wave][l15][32 + quad * 8];
#pragma unroll
        for (int nt = 0; nt < 4; ++nt) {
            const int dk = nt * 16 + l15;
#pragma unroll
            for (int ks = 0; ks < 2; ++ks) {
                const short8 bv = *(const short8*)&Vts[dk][ks * 32 + quad * 8];
                oacc[nt] = __builtin_amdgcn_mfma_f32_16x16x32_bf16(af[ks], bv, oacc[nt], 0, 0, 0);
            }
        }
        lacc = __builtin_amdgcn_mfma_f32_16x16x32_bf16(af[0], bones, lacc, 0, 0, 0);
        lacc = __builtin_amdgcn_mfma_f32_16x16x32_bf16(af[1], bones, lacc, 0, 0, 0);
        __syncthreads();   // LDS tiles free before restaging
    }

    // --- epilogue: broadcast l from col-0 lanes, normalize, write bf16 ---
#pragma unroll
    for (int r = 0; r < 4; ++r) {
        const float lsum = __shfl(lacc[r], (lane & 48));   // lane quad*16 (l15==0)
        const float inv  = 1.0f / lsum;
        const int qg = q0 + wave * 16 + quad * 4 + r;
        unsigned short* op = Ocb + (size_t)qg * DMODEL + h * 64 + l15;
#pragma unroll
        for (int nt = 0; nt < 4; ++nt)
            op[nt * 16] = f2bf(oacc[nt][r] * inv);
    }
}

extern "C" void kernel_launch(void* const* d_in, const int* in_sizes, int n_in,
                              void* d_out, int out_size, void* d_ws, size_t ws_size,
                              hipStream_t stream)
{
    const float* Q  = (const float*)d_in[0];
    const float* K  = (const float*)d_in[1];
    const float* V  = (const float*)d_in[2];
    const float* WQ = (const float*)d_in[3];
    const float* WK = (const float*)d_in[4];
    const float* WV = (const float*)d_in[5];
    const float* WO = (const float*)d_in[6];

    float* out = (float*)d_out;

    const size_t SD4 = (size_t)S * DMODEL * 4;       // fp32 S x D  (16 MB)
    const size_t SD2 = (size_t)S * DMODEL * 2;       // bf16 S x D  ( 8 MB)
    const size_t W2  = (size_t)DMODEL * DMODEL * 2;  // bf16 D x D  ( 2 MB)
    char* p = (char*)d_ws;
    auto take = [&](size_t b) { char* r = p; p += b; return r; };

    float* Qc = (float*)take(SD4);
    unsigned short* KHg = (unsigned short*)take(SD2);
    unsigned short* KLg = (unsigned short*)take(SD2);
    unsigned short* Vtg = (unsigned short*)take(SD2);   // bf16 [1024][4096]
    unsigned short* XqH = (unsigned short*)take(SD2);
    unsigned short* XqL = (unsigned short*)take(SD2);
    unsigned short* XkH = (unsigned short*)take(SD2);
    unsigned short* XkL = (unsigned short*)take(SD2);
    unsigned short* Xv  = (unsigned short*)take(SD2);
    unsigned short* WqtH = (unsigned short*)take(W2);
    unsigned short* WqtL = (unsigned short*)take(W2);
    unsigned short* WktH = (unsigned short*)take(W2);
    unsigned short* WktL = (unsigned short*)take(W2);
    unsigned short* Wvt  = (unsigned short*)take(W2);
    unsigned short* WOt  = (unsigned short*)take(W2);
    unsigned short* Ocb  = (unsigned short*)take(SD2);

    // 1) input splits + all weight transposes in ONE launch
    prep_all<<<dim3(2048, 1, 4), 256, 0, stream>>>(
        Q, K, V, WQ, WK, WV, WO,
        XqH, XqL, XkH, XkL, Xv, WqtH, WqtL, WktH, WktL, Wvt, WOt);
    // 2) projections: Q -> fp32 Qc; K -> bf16 hi/lo direct; V -> bf16 Vt direct
    proj_mfma<<<dim3(S / 128, DMODEL / 128, 3), 256, 0, stream>>>(
        XqH, XqL, XkH, XkL, Xv, WqtH, WqtL, WktH, WktL, Wvt, Qc, KHg, KLg, Vtg);
    // 3) causal flash attention -> bf16 Ocb  (8-wave QBLK=128 blocks)
    attn_mfma<<<dim3((S / 128) * H), 512, 0, stream>>>(Qc, KHg, KLg, Vtg, Ocb);
    // 4) output projection
    out_gemm_mfma<<<dim3(S / 128, DMODEL / 128), 256, 0, stream>>>(Ocb, WOt, out);
}

// Round 7
// 328.114 us; speedup vs baseline: 1.0229x; 1.0145x over previous
//
#include <hip/hip_runtime.h>
#include <hip/hip_bf16.h>

// Problem constants
constexpr int S      = 4096;
constexpr int DMODEL = 1024;
constexpr int H      = 16;
constexpr int DK     = 64;

typedef __attribute__((ext_vector_type(8))) short          short8;
typedef __attribute__((ext_vector_type(4))) short          short4v;
typedef __attribute__((ext_vector_type(4))) float          float4v;
typedef __attribute__((ext_vector_type(4))) unsigned short ushort4v;
typedef __attribute__((ext_vector_type(8))) unsigned short ushort8;

// RNE float -> bf16 (bit pattern), and back
__device__ __forceinline__ unsigned short f2bf(float x) {
    unsigned u = __builtin_bit_cast(unsigned, x);
    u += 0x7FFFu + ((u >> 16) & 1u);
    return (unsigned short)(u >> 16);
}
__device__ __forceinline__ float bf2f(unsigned short h) {
    unsigned u = ((unsigned)h) << 16;
    return __builtin_bit_cast(float, u);
}
__device__ __forceinline__ float fexp2(float x) { return __builtin_amdgcn_exp2f(x); }

// packed f32x2 -> bf16x2 (RNE, same rounding as f2bf); no builtin on gfx950
__device__ __forceinline__ unsigned cvtpk_bf16(float lo, float hi) {
    unsigned r;
    asm("v_cvt_pk_bf16_f32 %0, %1, %2" : "=v"(r) : "v"(lo), "v"(hi));
    return r;
}

// async global->LDS DMA, 16B per lane; lds dest = wave-uniform base + lane*16
__device__ __forceinline__ void gl_lds16(const unsigned short* g, unsigned short* l) {
    __builtin_amdgcn_global_load_lds(
        (const __attribute__((address_space(1))) unsigned int*)g,
        (__attribute__((address_space(3))) unsigned int*)l, 16, 0, 0);
}

// ---------------------------------------------------------------------------
// Prep (fused): elementwise split of X inputs (z=0..2) + all four weight
// transposes (z=3).  Verbatim (passed round 3).
// ---------------------------------------------------------------------------
__global__ __launch_bounds__(256) void prep_all(
    const float* __restrict__ Q, const float* __restrict__ K,
    const float* __restrict__ V,
    const float* __restrict__ WQ, const float* __restrict__ WK,
    const float* __restrict__ WV, const float* __restrict__ WO,
    unsigned short* __restrict__ QH, unsigned short* __restrict__ QL,
    unsigned short* __restrict__ KH, unsigned short* __restrict__ KL,
    unsigned short* __restrict__ Vb,
    unsigned short* __restrict__ WqtH, unsigned short* __restrict__ WqtL,
    unsigned short* __restrict__ WktH, unsigned short* __restrict__ WktL,
    unsigned short* __restrict__ Wvt,  unsigned short* __restrict__ WOt)
{
    const int zb = blockIdx.z;
    const int t  = threadIdx.x;

    if (zb < 3) {
        // ---- input split path (2048 blocks per z) ----
        const size_t base = ((size_t)blockIdx.x * 256 + t) * 8;
        const float* src = (zb == 0) ? Q : (zb == 1) ? K : V;
        const float4 a = *(const float4*)(src + base);
        const float4 b = *(const float4*)(src + base + 4);
        const float xs[8] = {a.x, a.y, a.z, a.w, b.x, b.y, b.z, b.w};
        ushort8 hv, lv;
#pragma unroll
        for (int j = 0; j < 8; ++j) {
            const unsigned short h = f2bf(xs[j]);
            hv[j] = h;
            lv[j] = f2bf(xs[j] - bf2f(h));
        }
        if (zb == 0)      { *(ushort8*)(QH + base) = hv; *(ushort8*)(QL + base) = lv; }
        else if (zb == 1) { *(ushort8*)(KH + base) = hv; *(ushort8*)(KL + base) = lv; }
        else              { *(ushort8*)(Vb + base) = hv; }
        return;
    }

    // ---- weight transpose path (first 1024 blocks of z=3) ----
    const int bb = blockIdx.x;
    if (bb >= 1024) return;
    const int zfull = bb >> 4;          // old blockIdx.z (0..63)
    const int which = zfull >> 4;
    const int z     = zfull & 15;
    const int r0    = (bb & 15) * 64;   // old blockIdx.x * 64

    __shared__ float Ts[64][65];

    const float* in;
    unsigned short *oh, *ol;
    int z_mult, rstride;
    if (which == 0)      { in = WQ; oh = WqtH; ol = WqtL; z_mult = 65536; rstride = 64; }
    else if (which == 1) { in = WK; oh = WktH; ol = WktL; z_mult = 65536; rstride = 64; }
    else if (which == 2) { in = WV; oh = Wvt;  ol = nullptr; z_mult = 65536; rstride = 64; }
    else                 { in = WO; oh = WOt;  ol = nullptr; z_mult = 64;    rstride = 1024; }

    const float* src = in + (size_t)z * z_mult;
#pragma unroll
    for (int i = 0; i < 4; ++i) {
        const int row = (t >> 4) + i * 16;
        const int col = (t & 15) * 4;
        const float4 v = *(const float4*)&src[(size_t)(r0 + row) * rstride + col];
        Ts[row][col + 0] = v.x; Ts[row][col + 1] = v.y;
        Ts[row][col + 2] = v.z; Ts[row][col + 3] = v.w;
    }
    __syncthreads();
#pragma unroll
    for (int i = 0; i < 4; ++i) {
        const int c  = (t >> 4) + i * 16;
        const int rb = (t & 15) * 4;
        ushort4v hv, lv;
#pragma unroll
        for (int j = 0; j < 4; ++j) {
            const float x = Ts[rb + j][c];
            const unsigned short h = f2bf(x);
            hv[j] = h;
            lv[j] = f2bf(x - bf2f(h));
        }
        const size_t o = (size_t)(z * 64 + c) * 1024 + r0 + rb;
        *(ushort4v*)&oh[o] = hv;
        if (ol) *(ushort4v*)&ol[o] = lv;
    }
}

// ---------------------------------------------------------------------------
// bf16 MFMA GEMM core (global_load_lds width=16 staging).  Verbatim.
// EPI=0: fp32 -> C.
// EPI=1: bf16 hi/lo split -> O1/O2.
// EPI=2: TRANSPOSED bf16 -> O1 (pitch 4096), replaces transpose_v bit-exactly.
// ---------------------------------------------------------------------------
template <bool SPLIT, int EPI>
__device__ __forceinline__ void gemm_core(unsigned short* __restrict__ sm,
                                          const unsigned short* __restrict__ Ah,
                                          const unsigned short* __restrict__ Al,
                                          const unsigned short* __restrict__ Bh,
                                          const unsigned short* __restrict__ Bl,
                                          float* __restrict__ C,
                                          unsigned short* __restrict__ O1,
                                          unsigned short* __restrict__ O2,
                                          int m0, int n0)
{
    unsigned short* AsH = sm;            // [128][32]
    unsigned short* BsH = sm + 4096;
    unsigned short* AsL = sm + 8192;     // SPLIT only
    unsigned short* BsL = sm + 12288;

    const int t    = threadIdx.x;
    const int wave = t >> 6;
    const int lane = t & 63;
    const int quad = lane >> 4;
    const int l15  = lane & 15;
    const int wm   = (wave & 1) * 64;
    const int wn   = (wave >> 1) * 64;

    float4v acc[4][4];
#pragma unroll
    for (int mi = 0; mi < 4; ++mi)
#pragma unroll
        for (int ni = 0; ni < 4; ++ni)
#pragma unroll
            for (int r = 0; r < 4; ++r) acc[mi][ni][r] = 0.f;

    for (int k0 = 0; k0 < 1024; k0 += 32) {
        __syncthreads();   // prior iteration's LDS reads complete
#pragma unroll
        for (int i = 0; i < 2; ++i) {
            const int c   = t + 256 * i;
            const int row = c >> 2;
            const int kc  = (c & 3) * 8;
            const int lb  = (i * 256 + wave * 64) * 8;   // wave-uniform base (shorts)
            gl_lds16(&Ah[(size_t)(m0 + row) * 1024 + k0 + kc], AsH + lb);
            gl_lds16(&Bh[(size_t)(n0 + row) * 1024 + k0 + kc], BsH + lb);
            if (SPLIT) {
                gl_lds16(&Al[(size_t)(m0 + row) * 1024 + k0 + kc], AsL + lb);
                gl_lds16(&Bl[(size_t)(n0 + row) * 1024 + k0 + kc], BsL + lb);
            }
        }
        __syncthreads();   // vmcnt drained before barrier -> data visible

        short8 afh[4], bfh[4], afl[4], bfl[4];
#pragma unroll
        for (int mi = 0; mi < 4; ++mi)
            afh[mi] = *(const short8*)&AsH[(wm + mi * 16 + l15) * 32 + quad * 8];
#pragma unroll
        for (int ni = 0; ni < 4; ++ni)
            bfh[ni] = *(const short8*)&BsH[(wn + ni * 16 + l15) * 32 + quad * 8];
        if (SPLIT) {
#pragma unroll
            for (int mi = 0; mi < 4; ++mi)
                afl[mi] = *(const short8*)&AsL[(wm + mi * 16 + l15) * 32 + quad * 8];
#pragma unroll
            for (int ni = 0; ni < 4; ++ni)
                bfl[ni] = *(const short8*)&BsL[(wn + ni * 16 + l15) * 32 + quad * 8];
        }

#pragma unroll
        for (int mi = 0; mi < 4; ++mi)
#pragma unroll
            for (int ni = 0; ni < 4; ++ni) {
                acc[mi][ni] = __builtin_amdgcn_mfma_f32_16x16x32_bf16(
                    afh[mi], bfh[ni], acc[mi][ni], 0, 0, 0);
                if (SPLIT) {
                    acc[mi][ni] = __builtin_amdgcn_mfma_f32_16x16x32_bf16(
                        afh[mi], bfl[ni], acc[mi][ni], 0, 0, 0);
                    acc[mi][ni] = __builtin_amdgcn_mfma_f32_16x16x32_bf16(
                        afl[mi], bfh[ni], acc[mi][ni], 0, 0, 0);
                }
            }
    }

    if (EPI == 2) {
        // fused transpose epilogue: acc(m,n) -> O1[n][m] bf16
        __syncthreads();               // all waves done with As/Bs LDS reads
        unsigned short* Ts = sm;       // [128][136] pitch in shorts
#pragma unroll
        for (int mi = 0; mi < 4; ++mi)
#pragma unroll
            for (int ni = 0; ni < 4; ++ni) {
                ushort4v pk;
#pragma unroll
                for (int r = 0; r < 4; ++r) pk[r] = f2bf(acc[mi][ni][r]);
                *(ushort4v*)&Ts[(wn + ni * 16 + l15) * 136 + wm + mi * 16 + quad * 4] = pk;
            }
        __syncthreads();
#pragma unroll
        for (int p = 0; p < 8; ++p) {
            const int n = p * 16 + (t >> 4);
            const int m = (t & 15) * 8;
            *(ushort8*)&O1[(size_t)(n0 + n) * 4096 + m0 + m] =
                *(const ushort8*)&Ts[n * 136 + m];
        }
        return;
    }

#pragma unroll
    for (int mi = 0; mi < 4; ++mi)
#pragma unroll
        for (int r = 0; r < 4; ++r) {
            const int m = m0 + wm + mi * 16 + quad * 4 + r;
            if (EPI == 0) {
                float* cp = C + (size_t)m * 1024 + n0 + wn + l15;
#pragma unroll
                for (int ni = 0; ni < 4; ++ni) cp[ni * 16] = acc[mi][ni][r];
            } else {
                unsigned short* o1 = O1 + (size_t)m * 1024 + n0 + wn + l15;
                unsigned short* o2 = O2 + (size_t)m * 1024 + n0 + wn + l15;
#pragma unroll
                for (int ni = 0; ni < 4; ++ni) {
                    const float v = acc[mi][ni][r];
                    const unsigned short hh = f2bf(v);
                    o1[ni * 16] = hh;
                    o2[ni * 16] = f2bf(v - bf2f(hh));
                }
            }
        }
}

// Fused projections: z=0 Q(split->fp32 Qc), z=1 K(split->bf16 hi/lo direct),
// z=2 V(plain->bf16 TRANSPOSED Vt direct)
__global__ __launch_bounds__(256) void proj_mfma(
    const unsigned short* __restrict__ XqH, const unsigned short* __restrict__ XqL,
    const unsigned short* __restrict__ XkH, const unsigned short* __restrict__ XkL,
    const unsigned short* __restrict__ Xv,
    const unsigned short* __restrict__ WqtH, const unsigned short* __restrict__ WqtL,
    const unsigned short* __restrict__ WktH, const unsigned short* __restrict__ WktL,
    const unsigned short* __restrict__ Wvt,
    float* __restrict__ Qc,
    unsigned short* __restrict__ KHg, unsigned short* __restrict__ KLg,
    unsigned short* __restrict__ Vt)
{
    // max(SPLIT staging 4*4096, EPI2 transpose 128*136) shorts
    __shared__ __align__(16) unsigned short smem[17408];
    const int m0 = blockIdx.x * 128, n0 = blockIdx.y * 128;
    if (blockIdx.z == 0)
        gemm_core<true, 0>(smem, XqH, XqL, WqtH, WqtL, Qc, nullptr, nullptr, m0, n0);
    else if (blockIdx.z == 1)
        gemm_core<true, 1>(smem, XkH, XkL, WktH, WktL, nullptr, KHg, KLg, m0, n0);
    else
        gemm_core<false, 2>(smem, Xv, nullptr, Wvt, nullptr, nullptr, Vt, nullptr, m0, n0);
}

__global__ __launch_bounds__(256) void out_gemm_mfma(
    const unsigned short* __restrict__ Ocb,
    const unsigned short* __restrict__ WOt,
    float* __restrict__ out)
{
    __shared__ __align__(16) unsigned short smem[2 * 4096];
    gemm_core<false, 0>(smem, Ocb, nullptr, WOt, nullptr, out, nullptr, nullptr,
                        blockIdx.x * 128, blockIdx.y * 128);
}

// ---------------------------------------------------------------------------
// MFMA flash attention — 8-wave QBLK=128 (round-3, 136.6 µs measured) +
// VALU-TRIM (resubmitted verbatim; three infra-only bench failures).
// Counters motivating this: VALUBusy 35.7%, MfmaUtil 23%, 42% idle ->
// softmax VALU chain dominates; MFMA floor is ~20 µs.
//   1. SCL folded into exp2 via fma (rmax in raw domain, m_r scaled).
//   2. Mask cndmask only on true crossing tiles; raw-domain constant -1e10.
//   3. Skip-rescale when no row max grows (__any): alpha==1.0 exactly ->
//      skipping is BIT-IDENTICAL.  ~90% of tiles skip.
//   4. Fully-masked tiles skip QK/softmax/PV entirely: P==0 exactly ->
//      bit-identical.  All waves still hit both barriers (uniform).
//   5. P-pack via v_cvt_pk_bf16_f32 (RNE, same rounding as f2bf).
// ---------------------------------------------------------------------------
__global__ __launch_bounds__(512) void attn_mfma(const float* __restrict__ Qc,
                                                 const unsigned short* __restrict__ KHg,
                                                 const unsigned short* __restrict__ KLg,
                                                 const unsigned short* __restrict__ Vtg,
                                                 unsigned short* __restrict__ Ocb)
{
    __shared__ __align__(16) short Khi[64][72];
    __shared__ __align__(16) short Klo[64][72];
    __shared__ __align__(16) short Vts[64][72];   // [dk][key]
    __shared__ __align__(16) short Pb[8][16][72];

    const int bid = blockIdx.x;
    const int h   = bid & 15;
    const int g   = bid >> 4;                       // 0..31
    const int qb  = (g < 16) ? (31 - g) : (g - 16); // long/short pairing
    const int q0  = qb * 128;
    const int jtmax = 2 * qb + 1;

    const int t    = threadIdx.x;
    const int wave = t >> 6;      // 0..7
    const int lane = t & 63;
    const int quad = lane >> 4;
    const int l15  = lane & 15;

    constexpr float SCL = 0.18033688011112042f;   // 0.125 * log2(e)

    // Q A-fragments, split hi/lo from fp32 (once per block)
    short8 qhi[2], qlo[2];
    {
        const int qrow = q0 + wave * 16 + l15;
        const float* qp = Qc + (size_t)qrow * DMODEL + h * 64 + quad * 8;
#pragma unroll
        for (int ks = 0; ks < 2; ++ks) {
            float4 a = *(const float4*)(qp + ks * 32);
            float4 b = *(const float4*)(qp + ks * 32 + 4);
            const float xs[8] = {a.x, a.y, a.z, a.w, b.x, b.y, b.z, b.w};
#pragma unroll
            for (int j = 0; j < 8; ++j) {
                const unsigned short hi = f2bf(xs[j]);
                const unsigned short lo = f2bf(xs[j] - bf2f(hi));
                qhi[ks][j] = (short)hi;
                qlo[ks][j] = (short)lo;
            }
        }
    }

    // all-ones B fragment: B[k][0] = 1.0, other cols 0  (row-sum MFMA)
    short8 bones;
    {
        const short ob = (l15 == 0) ? (short)0x3F80 : (short)0;
#pragma unroll
        for (int j = 0; j < 8; ++j) bones[j] = ob;
    }

    float m_r[4] = {-1e30f, -1e30f, -1e30f, -1e30f};
    float4v lacc;
    float4v oacc[4];
#pragma unroll
    for (int r = 0; r < 4; ++r) lacc[r] = 0.f;
#pragma unroll
    for (int nt = 0; nt < 4; ++nt)
#pragma unroll
        for (int r = 0; r < 4; ++r) oacc[nt][r] = 0.f;

    // staging assignment: 512 threads cover 64 rows x 8 col-chunks
    const int srow = t >> 3;        // 0..63
    const int soff = (t & 7) * 8;   // 0..56

    // prefetch registers, initial load for jt = 0
    ushort8 kh, kl, vt;
    kh = *(const ushort8*)&KHg[(size_t)srow * 1024 + h * 64 + soff];
    kl = *(const ushort8*)&KLg[(size_t)srow * 1024 + h * 64 + soff];
    vt = *(const ushort8*)&Vtg[(size_t)(h * 64 + srow) * 4096 + soff];

    const int qrow_lo = q0 + wave * 16;         // this wave's first q row
    for (int jt = 0; jt <= jtmax; ++jt) {
        const int j0 = jt * 64;
        // --- stage prefetched vectors (ds_write_b128) ---
        *(ushort8*)&Khi[srow][soff] = kh;
        *(ushort8*)&Klo[srow][soff] = kl;
        *(ushort8*)&Vts[srow][soff] = vt;
        __syncthreads();

        // --- prefetch next tile (overlaps compute below) ---
        if (jt < jtmax) {
            const int jn = j0 + 64;
            kh = *(const ushort8*)&KHg[(size_t)(jn + srow) * 1024 + h * 64 + soff];
            kl = *(const ushort8*)&KLg[(size_t)(jn + srow) * 1024 + h * 64 + soff];
            vt = *(const ushort8*)&Vtg[(size_t)(h * 64 + srow) * 4096 + jn + soff];
        }

        // tile fully past this wave's diagonal -> P == 0 exactly; skip all
        // compute (bit-identical).  Still hits the end barrier below.
        if (j0 <= qrow_lo + 15) {
            // --- S = Q K^T (split bf16, fp32 accum), RAW domain ---
            float4v sacc[4];
#pragma unroll
            for (int nt = 0; nt < 4; ++nt)
#pragma unroll
                for (int r = 0; r < 4; ++r) sacc[nt][r] = 0.f;
#pragma unroll
            for (int nt = 0; nt < 4; ++nt) {
                const int key = nt * 16 + l15;
#pragma unroll
                for (int ks = 0; ks < 2; ++ks) {
                    const short8 bh = *(const short8*)&Khi[key][ks * 32 + quad * 8];
                    const short8 bl = *(const short8*)&Klo[key][ks * 32 + quad * 8];
                    sacc[nt] = __builtin_amdgcn_mfma_f32_16x16x32_bf16(qhi[ks], bh, sacc[nt], 0, 0, 0);
                    sacc[nt] = __builtin_amdgcn_mfma_f32_16x16x32_bf16(qhi[ks], bl, sacc[nt], 0, 0, 0);
                    sacc[nt] = __builtin_amdgcn_mfma_f32_16x16x32_bf16(qlo[ks], bh, sacc[nt], 0, 0, 0);
                }
            }

            // --- causal mask only on the crossing tile (raw domain) ---
            if (j0 + 63 > qrow_lo) {
#pragma unroll
                for (int nt = 0; nt < 4; ++nt) {
                    const int jg = j0 + nt * 16 + l15;
#pragma unroll
                    for (int r = 0; r < 4; ++r) {
                        const int qg = qrow_lo + quad * 4 + r;
                        if (jg > qg) sacc[nt][r] = -1e10f;
                    }
                }
            }

            // --- row max (raw domain; SCL > 0 so comparisons transfer) ---
            float rmax[4];
#pragma unroll
            for (int r = 0; r < 4; ++r)
                rmax[r] = fmaxf(fmaxf(sacc[0][r], sacc[1][r]), fmaxf(sacc[2][r], sacc[3][r]));
#pragma unroll
            for (int off = 1; off < 16; off <<= 1)
#pragma unroll
                for (int r = 0; r < 4; ++r)
                    rmax[r] = fmaxf(rmax[r], __shfl_xor(rmax[r], off));

            // --- rescale only when some row max grows (else alpha==1.0:
            //     skipping is bit-identical) ---
            float rs[4];
#pragma unroll
            for (int r = 0; r < 4; ++r) rs[r] = rmax[r] * SCL;
            const bool grow = (rs[0] > m_r[0]) || (rs[1] > m_r[1]) ||
                              (rs[2] > m_r[2]) || (rs[3] > m_r[3]);
            if (__any(grow)) {
#pragma unroll
                for (int r = 0; r < 4; ++r) {
                    const float mn   = fmaxf(m_r[r], rs[r]);
                    const float alpha = fexp2(m_r[r] - mn);
                    m_r[r] = mn;
                    lacc[r] *= alpha;
#pragma unroll
                    for (int nt = 0; nt < 4; ++nt) oacc[nt][r] *= alpha;
                }
            }

            // --- P = exp2(fma(raw, SCL, -m)) ; pack via v_cvt_pk_bf16_f32 ---
#pragma unroll
            for (int nt = 0; nt < 4; ++nt)
#pragma unroll
                for (int r = 0; r < 4; ++r)
                    sacc[nt][r] = fexp2(__builtin_fmaf(sacc[nt][r], SCL, -m_r[r]));

#pragma unroll
            for (int r = 0; r < 4; ++r) {
                const int prow = quad * 4 + r;
#pragma unroll
                for (int np = 0; np < 2; ++np) {
                    const unsigned w = cvtpk_bf16(sacc[2 * np][r], sacc[2 * np + 1][r]);
                    Pb[wave][prow][(2 * np) * 16 + l15]     = (short)(w & 0xffffu);
                    Pb[wave][prow][(2 * np + 1) * 16 + l15] = (short)(w >> 16);
                }
            }
            __asm__ volatile("s_waitcnt lgkmcnt(0)" ::: "memory");

            // --- O += P @ V, and l += P @ 1 ---
            short8 af[2];
            af[0] = *(const short8*)&Pb[wave][l15][quad * 8];
            af[1] = *(const short8*)&Pb[wave][l15][32 + quad * 8];
#pragma unroll
            for (int nt = 0; nt < 4; ++nt) {
                const int dk = nt * 16 + l15;
#pragma unroll
                for (int ks = 0; ks < 2; ++ks) {
                    const short8 bv = *(const short8*)&Vts[dk][ks * 32 + quad * 8];
                    oacc[nt] = __builtin_amdgcn_mfma_f32_16x16x32_bf16(af[ks], bv, oacc[nt], 0, 0, 0);
                }
            }
            lacc = __builtin_amdgcn_mfma_f32_16x16x32_bf16(af[0], bones, lacc, 0, 0, 0);
            lacc = __builtin_amdgcn_mfma_f32_16x16x32_bf16(af[1], bones, lacc, 0, 0, 0);
        }
        __syncthreads();   // LDS tiles free before restaging (all waves)
    }

    // --- epilogue: broadcast l from col-0 lanes, normalize, write bf16 ---
#pragma unroll
    for (int r = 0; r < 4; ++r) {
        const float lsum = __shfl(lacc[r], (lane & 48));   // lane quad*16 (l15==0)
        const float inv  = 1.0f / lsum;
        const int qg = q0 + wave * 16 + quad * 4 + r;
        unsigned short* op = Ocb + (size_t)qg * DMODEL + h * 64 + l15;
#pragma unroll
        for (int nt = 0; nt < 4; ++nt)
            op[nt * 16] = f2bf(oacc[nt][r] * inv);
    }
}

extern "C" void kernel_launch(void* const* d_in, const int* in_sizes, int n_in,
                              void* d_out, int out_size, void* d_ws, size_t ws_size,
                              hipStream_t stream)
{
    const float* Q  = (const float*)d_in[0];
    const float* K  = (const float*)d_in[1];
    const float* V  = (const float*)d_in[2];
    const float* WQ = (const float*)d_in[3];
    const float* WK = (const float*)d_in[4];
    const float* WV = (const float*)d_in[5];
    const float* WO = (const float*)d_in[6];

    float* out = (float*)d_out;

    const size_t SD4 = (size_t)S * DMODEL * 4;       // fp32 S x D  (16 MB)
    const size_t SD2 = (size_t)S * DMODEL * 2;       // bf16 S x D  ( 8 MB)
    const size_t W2  = (size_t)DMODEL * DMODEL * 2;  // bf16 D x D  ( 2 MB)
    char* p = (char*)d_ws;
    auto take = [&](size_t b) { char* r = p; p += b; return r; };

    float* Qc = (float*)take(SD4);
    unsigned short* KHg = (unsigned short*)take(SD2);
    unsigned short* KLg = (unsigned short*)take(SD2);
    unsigned short* Vtg = (unsigned short*)take(SD2);   // bf16 [1024][4096]
    unsigned short* XqH = (unsigned short*)take(SD2);
    unsigned short* XqL = (unsigned short*)take(SD2);
    unsigned short* XkH = (unsigned short*)take(SD2);
    unsigned short* XkL = (unsigned short*)take(SD2);
    unsigned short* Xv  = (unsigned short*)take(SD2);
    unsigned short* WqtH = (unsigned short*)take(W2);
    unsigned short* WqtL = (unsigned short*)take(W2);
    unsigned short* WktH = (unsigned short*)take(W2);
    unsigned short* WktL = (unsigned short*)take(W2);
    unsigned short* Wvt  = (unsigned short*)take(W2);
    unsigned short* WOt  = (unsigned short*)take(W2);
    unsigned short* Ocb  = (unsigned short*)take(SD2);

    // 1) input splits + all weight transposes in ONE launch
    prep_all<<<dim3(2048, 1, 4), 256, 0, stream>>>(
        Q, K, V, WQ, WK, WV, WO,
        XqH, XqL, XkH, XkL, Xv, WqtH, WqtL, WktH, WktL, Wvt, WOt);
    // 2) projections: Q -> fp32 Qc; K -> bf16 hi/lo direct; V -> bf16 Vt direct
    proj_mfma<<<dim3(S / 128, DMODEL / 128, 3), 256, 0, stream>>>(
        XqH, XqL, XkH, XkL, Xv, WqtH, WqtL, WktH, WktL, Wvt, Qc, KHg, KLg, Vtg);
    // 3) causal flash attention -> bf16 Ocb  (8-wave QBLK=128, VALU-trimmed)
    attn_mfma<<<dim3((S / 128) * H), 512, 0, stream>>>(Qc, KHg, KLg, Vtg, Ocb);
    // 4) output projection
    out_gemm_mfma<<<dim3(S / 128, DMODEL / 128), 256, 0, stream>>>(Ocb, WOt, out);
}